// Round 14
// baseline (83.107 us; speedup 1.0000x reference)
//
#include <hip/hip_runtime.h>

// Patch gather, row-major scatter + PLAIN stores + conflict-free LDS.
// out[n, r-p0, c] = images[r, p1+c] for each patch n overlapping image row r.
//
// Model (R8-R13): nt stores drain at ~4.1-4.7 TB/s in every schedule; plain
// full-line stores hit 7 TB/s with no RFO (memset-proven: WRITE 1GB,
// FETCH 22MB). Plain write-allocation only hurts when reads need cache
// retention -- the row-scatter structure removes that need (block-exclusive
// staged reads, compulsory 64 MB). R10 (scatter+plain, 89.5us) failed on
// STRUCTURE: 8 waves/CU, serial per-patch loop, 4-8-way LDS conflicts.
// Fixes here:
//  - ROWS=2 -> 33 KB LDS -> 4 blocks/CU = 16 waves/CU, 2048 blocks
//  - pad-swizzled LDS (slot = c + c/32): stride-4 float reads from
//    arbitrary p1 are conflict-free across the 32-lane group
//  - nr<=2 -> inner loop is ONE plain dwordx4 store per item (sub-half of
//    the wave takes row rlo+sub): 1 KB contiguous per full item
//
//  1) order_kernel (1 block): exact counting sort of patches by p0
//     (4096 bins) -> rec[] {n,p0,p1}, prefix row_start[4097].
//  2) row_scatter_kernel (2048 blocks): block b stages image rows [2b,2b+2)
//     into swizzled LDS, then scatters to patches with p0 in [2b-127, 2b+1].

#define IMG_W   4096
#define IMG_H   4096
#define PATCH_W 128
#define BLOCK   256
#define ROWS    2
#define PADW    (IMG_W + IMG_W / 32)   // 4224 floats per padded LDS row
#define NBINS   4096

typedef float f32x4 __attribute__((ext_vector_type(4)));

__global__ __launch_bounds__(1024) void order_kernel(
    const int* __restrict__ positions,
    int4*      __restrict__ rec,
    int*       __restrict__ row_start,   // NBINS+1 ints
    int N)
{
    __shared__ int hist[NBINS];      // 16 KB
    __shared__ int partial[1024];    // 4 KB
    const int tid = threadIdx.x;

    #pragma unroll
    for (int j = 0; j < NBINS / 1024; ++j) hist[tid + j * 1024] = 0;
    __syncthreads();

    for (int i = tid; i < N; i += 1024) {
        const int2 p = ((const int2*)positions)[i];
        atomicAdd(&hist[p.x], 1);
    }
    __syncthreads();

    // two-level exclusive scan: thread t owns bins [4t, 4t+4)
    const int b0 = tid * (NBINS / 1024);
    int s = 0;
    #pragma unroll
    for (int j = 0; j < NBINS / 1024; ++j) s += hist[b0 + j];
    partial[tid] = s;
    __syncthreads();

    for (int off = 1; off < 1024; off <<= 1) {
        const int v   = partial[tid];
        const int add = (tid >= off) ? partial[tid - off] : 0;
        __syncthreads();
        partial[tid] = v + add;
        __syncthreads();
    }

    int running = partial[tid] - s;  // exclusive base of this thread's bins
    #pragma unroll
    for (int j = 0; j < NBINS / 1024; ++j) {
        const int b   = b0 + j;
        const int cnt = hist[b];
        row_start[b] = running;
        hist[b]      = running;      // becomes scatter cursor
        running += cnt;
    }
    if (tid == 1023) row_start[NBINS] = running;   // == N
    __syncthreads();

    for (int i = tid; i < N; i += 1024) {
        const int2 p = ((const int2*)positions)[i];
        const int slot = atomicAdd(&hist[p.x], 1);
        rec[slot] = make_int4(i, p.x, p.y, 0);
    }
}

__global__ __launch_bounds__(BLOCK) void row_scatter_kernel(
    const float* __restrict__ images,
    const int4*  __restrict__ rec,
    const int*   __restrict__ row_start,
    float*       __restrict__ out)
{
    __shared__ float rows[ROWS * PADW];   // 33792 B -> 4 blocks/CU
    const int tid    = threadIdx.x;
    const int base_r = blockIdx.x * ROWS;

    // stage 2 image rows, swizzled: float col c of row r -> slot r*PADW + c + c/32
    {
        const f32x4* src4 = (const f32x4*)(images + (size_t)base_r * IMG_W);
        #pragma unroll
        for (int it = 0; it < ROWS * IMG_W / 4 / BLOCK; ++it) {   // 8 iters
            const int  i  = it * BLOCK + tid;       // 4-float chunk index
            const f32x4 v = src4[i];
            const int  c0  = i << 2;                // float index in 2-row strip
            const int  row = c0 >> 12;              // / 4096
            const int  col = c0 & (IMG_W - 1);
            // col % 4 == 0 -> col..col+3 share the same 32-block -> contiguous
            const int  sl  = row * PADW + col + (col >> 5);
            rows[sl + 0] = v.x;
            rows[sl + 1] = v.y;
            rows[sl + 2] = v.z;
            rows[sl + 3] = v.w;
        }
    }
    __syncthreads();

    // candidate patches: p0 in [base_r-127, base_r+1]
    const int s0 = row_start[max(0, base_r - (PATCH_W - 1))];
    const int s1 = row_start[base_r + ROWS];

    const int wid = tid >> 6;          // wave id 0..3
    const int sub = (tid & 63) >> 5;   // half-wave = row within item (0/1)
    const int l5  = tid & 31;          // lane within half-wave

    for (int idx = s0 + wid; idx < s1; idx += BLOCK / 64) {
        const int4 rr = rec[idx];      // wave-uniform
        const int n = rr.x, p0 = rr.y, p1 = rr.z;
        const int rlo = max(p0, base_r);
        const int nr  = min(p0 + PATCH_W, base_r + ROWS) - rlo;  // 1 or 2

        if (sub < nr) {
            const int lr = (rlo - base_r) + sub;   // LDS row this half reads
            const int c  = p1 + (l5 << 2);
            const int b  = lr * PADW;
            f32x4 v;
            v.x = rows[b + (c + 0) + ((c + 0) >> 5)];
            v.y = rows[b + (c + 1) + ((c + 1) >> 5)];
            v.z = rows[b + (c + 2) + ((c + 2) >> 5)];
            v.w = rows[b + (c + 3) + ((c + 3) >> 5)];
            // plain store: full item = 1 KB contiguous (two 512 B rows)
            float* dp = out + (size_t)n * (PATCH_W * PATCH_W)
                            + (size_t)(rlo - p0 + sub) * PATCH_W + (l5 << 2);
            *reinterpret_cast<f32x4*>(dp) = v;
        }
    }
}

// Fallback (tiny ws): identity-order nt gather (~89 us, correct).
__global__ __launch_bounds__(BLOCK) void patch_gather_kernel(
    const float* __restrict__ images,
    const int*   __restrict__ positions,
    float*       __restrict__ out)
{
    const int n  = blockIdx.x;
    const int p0 = positions[2 * n];
    const int p1 = positions[2 * n + 1];

    const float* srcp = images + (size_t)p0 * IMG_W + p1;
    float*       dst  = out + (size_t)n * (PATCH_W * PATCH_W);

    #pragma unroll
    for (int it = 0; it < (PATCH_W * PATCH_W / 4) / BLOCK; ++it) {
        const int i = it * BLOCK + threadIdx.x;
        const int r = i >> 5;
        const int c = (i & 31) << 2;
        const float* s = srcp + (size_t)r * IMG_W + c;
        f32x4 v;
        v.x = s[0]; v.y = s[1]; v.z = s[2]; v.w = s[3];
        __builtin_nontemporal_store(
            v, reinterpret_cast<f32x4*>(dst + (size_t)r * PATCH_W + c));
    }
}

extern "C" void kernel_launch(void* const* d_in, const int* in_sizes, int n_in,
                              void* d_out, int out_size, void* d_ws, size_t ws_size,
                              hipStream_t stream) {
    const float* images    = (const float*)d_in[0];
    const int*   positions = (const int*)d_in[1];
    float* out = (float*)d_out;

    const int N = in_sizes[1] / 2;   // 4096 patches

    const size_t rec_off = 32768;    // row_start (16.4 KB) lives at offset 0
    const size_t need    = rec_off + (size_t)N * sizeof(int4);

    if (ws_size >= need) {
        int*  row_start = (int*)d_ws;
        int4* rec       = (int4*)((char*)d_ws + rec_off);
        order_kernel<<<1, 1024, 0, stream>>>(positions, rec, row_start, N);
        row_scatter_kernel<<<IMG_H / ROWS, BLOCK, 0, stream>>>(
            images, rec, row_start, out);
    } else {
        patch_gather_kernel<<<N, BLOCK, 0, stream>>>(images, positions, out);
    }
}